// Round 3
// baseline (40.372 us; speedup 1.0000x reference)
//
#include <hip/hip_runtime.h>
#include <math.h>

#define QMAX 128   // wavelet support: gauss fp32-underflows to exact 0 beyond t~82
#define ZCUT 1920  // outputs p < ZCUT are exactly zero (x index p-1920 < 0)
#define PAD  131   // zero-pad in front of x row in LDS; 131 ≡ 3 (mod 4) keeps fp4 reads aligned

// ---------------- Kernel 1: build W[16][QMAX] ----------------
__global__ void wavelet_build(const float* __restrict__ scales,
                              const float* __restrict__ f_mod,
                              const float* __restrict__ poly_mod,
                              const float* __restrict__ exp_mod,
                              const float* __restrict__ frac_order,
                              const float* __restrict__ phase_mod,
                              const int* __restrict__ istep,
                              float* __restrict__ Wout) {
    const int k = blockIdx.x;   // scale 0..15
    const int t = threadIdx.x;  // 0..127
    const int i = istep[0];
    const float PI2 = 6.28318530717958647692f;

    const float scale = scales[k];
    const float f = 1.0f / scale;
    const float fm = f_mod[i];
    const float* pm = poly_mod + i * 14;
    const float em0 = exp_mod[i];
    const float* fo = frac_order + i * 12;
    const float* ph = phase_mod + i * 3;

    const float sigma = fmaxf(fm / (PI2 * f), 1e-6f);
    const float tf = (float)t;
    const float arg = PI2 * f * tf;
    const float br = cosf(arg);
    const float bi = sinf(arg);

    float rp = pm[0];
    float sign = -1.0f;
    for (int j = 0; j < 6; ++j) {
        float c = (float)(j + 2);
        float sp = (tf > 0.0f) ? powf(tf, fo[j]) : 0.0f;
        float term = sp * c / powf(sigma, fo[j]) * c * pm[j + 1];
        rp += sign * term;
        sign = -sign;
    }
    float ipoly = pm[7];
    sign = -1.0f;
    for (int j = 6; j < 12; ++j) {
        float sp = (tf > 0.0f) ? powf(tf, fo[j]) : 0.0f;
        float term;
        if (j == 9) {
            term = sp * 5.0f / (powf(sigma, fo[j]) * 5.0f) * pm[j + 2];
        } else {
            float c = (float)(j - 4);
            term = sp * c / powf(sigma, fo[j]) * c * pm[j + 2];
        }
        ipoly += sign * term;
        sign = -sign;
    }

    const float gauss = em0 * expf(-tf * tf / (2.0f * sigma * sigma));
    const float rw = br * rp * gauss;
    const float iw = bi * ipoly * gauss;
    const float amp = rw + iw;

    float sq = amp * amp;
    #pragma unroll
    for (int off = 32; off > 0; off >>= 1) sq += __shfl_xor(sq, off, 64);
    __shared__ float wsum[2];
    if ((t & 63) == 0) wsum[t >> 6] = sq;
    __syncthreads();
    const float norm = sqrtf(wsum[0] + wsum[1]);

    const float samp = amp / norm;
    const float phase = atan2f(iw, rw);
    const float sphi = sinf(phase);
    const float cphi = cosf(phase);
    const float snc = (phase != 0.0f) ? (sphi / phase) : 1.0f;  // sinc(phase/pi)
    const float w = (samp * sphi * ph[0]) * (samp * cphi * ph[1]) * (samp * snc * ph[2]);
    Wout[k * QMAX + t] = w;
}

// ---------------- Kernel 2: FIR conv, writes diagonal rows out[b][k][:] ----------------
// y[b,k,p] = sum_q x[b,k,p+q-2047] * W[k,q]  (zero-padded x); p<ZCUT -> 0.
// One block per (b,k) row. Whole x row staged in LDS with PAD zeros in front.
__global__ __launch_bounds__(256) void conv_diag(const float* __restrict__ x,
                                                 const float* __restrict__ W,
                                                 float* __restrict__ out) {
    __shared__ __attribute__((aligned(16))) float xs[PAD + 4096];
    __shared__ __attribute__((aligned(16))) float Wl[QMAX];

    const int bk = blockIdx.x;  // 0..255 = b*16 + k
    const int b = bk >> 4;
    const int k = bk & 15;
    const int tid = threadIdx.x;

    if (tid < QMAX) Wl[tid] = W[k * QMAX + tid];
    const float* xrow = x + (size_t)bk * 4096;
    for (int li = tid; li < PAD + 4096; li += 256) {
        xs[li] = (li >= PAD) ? xrow[li - PAD] : 0.0f;
    }
    __syncthreads();

    float* orow = out + ((size_t)b * 256 + k) * 4096;

    #pragma unroll
    for (int v = 0; v < 4; ++v) {
        const int fidx = tid + 256 * v;   // float4 index within row
        const int p = 4 * fidx;
        float4 val = make_float4(0.0f, 0.0f, 0.0f, 0.0f);
        if (p >= ZCUT) {
            float acc[4] = {0.0f, 0.0f, 0.0f, 0.0f};
            const int base = PAD + p - 2047;  // ≡ 0 (mod 4), ≥ 4
            for (int q = 0; q < QMAX; q += 4) {
                float4 w4 = *(const float4*)&Wl[q];
                float4 x0 = *(const float4*)&xs[base + q];
                float4 x1 = *(const float4*)&xs[base + q + 4];
                float win[8] = {x0.x, x0.y, x0.z, x0.w,
                                x1.x, x1.y, x1.z, x1.w};
                float wv[4] = {w4.x, w4.y, w4.z, w4.w};
                #pragma unroll
                for (int j = 0; j < 4; ++j) {
                    #pragma unroll
                    for (int r = 0; r < 4; ++r) {
                        acc[r] = fmaf(win[r + j], wv[j], acc[r]);
                    }
                }
            }
            val = make_float4(acc[0], acc[1], acc[2], acc[3]);
        }
        *(float4*)&orow[p] = val;
    }
}

// ---------------- Kernel 3: streaming replicate out[b][r*16+k] = out[b][k], r=1..15 ----
// One block per destination row (3840 blocks). Pure copy: memset-shaped store
// stream (contiguous 16 KB per block), source rows (4 MB total) are L2/LLC-hot.
__global__ __launch_bounds__(256) void replicate_rows(float* __restrict__ out) {
    const int k = blockIdx.z;        // 0..15
    const int rr = blockIdx.y;       // 0..239 -> r = 1 + (rr>>4)... no: encode r,b below
    const int b = blockIdx.x;        // 0..15
    const int r = 1 + (rr & 15);     // 1..16? rr in [0,240): r index
    // rr encodes (r-1)*16 jump? simpler: rr in [0,15] only if gridDim.y==15.
    // We launch gridDim = (16 b, 15 r, 16 k): rr is r-1 here.
    const float* src = out + ((size_t)b * 256 + k) * 4096;
    float* dst = out + ((size_t)b * 256 + (size_t)(rr + 1) * 16 + k) * 4096;
    const int tid = threadIdx.x;
    (void)r;
    #pragma unroll
    for (int v = 0; v < 4; ++v) {
        const int fidx = tid + 256 * v;
        float4 val = *(const float4*)&src[4 * fidx];
        __builtin_nontemporal_store(val.x, &dst[4 * fidx + 0]);
        __builtin_nontemporal_store(val.y, &dst[4 * fidx + 1]);
        __builtin_nontemporal_store(val.z, &dst[4 * fidx + 2]);
        __builtin_nontemporal_store(val.w, &dst[4 * fidx + 3]);
    }
}

extern "C" void kernel_launch(void* const* d_in, const int* in_sizes, int n_in,
                              void* d_out, int out_size, void* d_ws, size_t ws_size,
                              hipStream_t stream) {
    const float* x          = (const float*)d_in[0];
    const float* scales     = (const float*)d_in[1];
    const float* f_mod      = (const float*)d_in[2];
    const float* poly_mod   = (const float*)d_in[3];
    const float* exp_mod    = (const float*)d_in[4];
    const float* frac_order = (const float*)d_in[5];
    const float* phase_mod  = (const float*)d_in[6];
    const int*   istep      = (const int*)d_in[7];
    float* out = (float*)d_out;
    float* Wbuf = (float*)d_ws;  // 16*128 floats = 8 KB

    wavelet_build<<<dim3(16), dim3(QMAX), 0, stream>>>(
        scales, f_mod, poly_mod, exp_mod, frac_order, phase_mod, istep, Wbuf);

    conv_diag<<<dim3(256), dim3(256), 0, stream>>>(x, Wbuf, out);

    replicate_rows<<<dim3(16, 15, 16), dim3(256), 0, stream>>>(out);
}

// Round 5
// 35.764 us; speedup vs baseline: 1.1288x; 1.1288x over previous
//
#include <hip/hip_runtime.h>
#include <math.h>

#define QMAX 128   // wavelet support: gauss fp32-underflows to exact 0 beyond t~82
#define ZCUT 1920  // outputs p < ZCUT are exactly zero (x index p-1920 < 0)
#define XPAD 127   // zeros ahead of x in LDS; xs[p+q-1920] = x[p+q-2047], 16B-aligned reads
#define XLEN 2176  // x samples actually reachable: max index 4095+127-2047 = 2175
#define XS_SZ 2304 // XPAD + XLEN + slack, rounded to 2304

typedef float vfloat4 __attribute__((ext_vector_type(4)));  // native vec for nontemporal

// ---------------- Kernel 1: per-block W[k] build + FIR conv of diagonal rows ----------
// Block bk = b*16+k computes W[k] in-block, then
// y[b,k,p] = sum_q x[b,k,p+q-2047] * W[k,q]  (zero-padded x); p<ZCUT -> 0,
// and writes it to out[b][k][:] (plain stores: K2 re-reads these rows).
__global__ __launch_bounds__(256) void conv_diag(const float* __restrict__ x,
                                                 const float* __restrict__ scales,
                                                 const float* __restrict__ f_mod,
                                                 const float* __restrict__ poly_mod,
                                                 const float* __restrict__ exp_mod,
                                                 const float* __restrict__ frac_order,
                                                 const float* __restrict__ phase_mod,
                                                 const int* __restrict__ istep,
                                                 float* __restrict__ out) {
    __shared__ __attribute__((aligned(16))) float xs[XS_SZ];
    __shared__ __attribute__((aligned(16))) float Wl[QMAX];
    __shared__ float wsum[2];

    const int bk = blockIdx.x;  // 0..255 = b*16 + k
    const int b = bk >> 4;
    const int k = bk & 15;
    const int tid = threadIdx.x;

    // ---- stage x[0..XLEN) behind XPAD zeros (all 256 threads) ----
    const float* xrow = x + (size_t)bk * 4096;
    for (int li = tid; li < XS_SZ; li += 256) {
        xs[li] = (li >= XPAD && li < XPAD + XLEN) ? xrow[li - XPAD] : 0.0f;
    }

    // ---- threads 0..127 compute the wavelet tap amp[t] ----
    float amp = 0.0f, rw = 0.0f, iw = 0.0f;
    if (tid < QMAX) {
        const int i = istep[0];
        const float PI2 = 6.28318530717958647692f;
        const float f = 1.0f / scales[k];
        const float fm = f_mod[i];
        const float* pm = poly_mod + i * 14;
        const float em0 = exp_mod[i];
        const float* fo = frac_order + i * 12;

        const float sigma = fmaxf(fm / (PI2 * f), 1e-6f);
        const float tf = (float)tid;
        const float arg = PI2 * f * tf;
        const float br = cosf(arg);
        const float bi = sinf(arg);

        float rp = pm[0];
        float sign = -1.0f;
        for (int j = 0; j < 6; ++j) {
            float c = (float)(j + 2);
            float sp = (tf > 0.0f) ? powf(tf, fo[j]) : 0.0f;
            float term = sp * c / powf(sigma, fo[j]) * c * pm[j + 1];
            rp += sign * term;
            sign = -sign;
        }
        float ipoly = pm[7];
        sign = -1.0f;
        for (int j = 6; j < 12; ++j) {
            float sp = (tf > 0.0f) ? powf(tf, fo[j]) : 0.0f;
            float term;
            if (j == 9) {
                term = sp * 5.0f / (powf(sigma, fo[j]) * 5.0f) * pm[j + 2];
            } else {
                float c = (float)(j - 4);
                term = sp * c / powf(sigma, fo[j]) * c * pm[j + 2];
            }
            ipoly += sign * term;
            sign = -sign;
        }

        const float gauss = em0 * expf(-tf * tf / (2.0f * sigma * sigma));
        rw = br * rp * gauss;
        iw = bi * ipoly * gauss;
        amp = rw + iw;

        float sq = amp * amp;
        #pragma unroll
        for (int off = 32; off > 0; off >>= 1) sq += __shfl_xor(sq, off, 64);
        if ((tid & 63) == 0) wsum[tid >> 6] = sq;
    }
    __syncthreads();

    if (tid < QMAX) {
        const int i = istep[0];
        const float* ph = phase_mod + i * 3;
        const float norm = sqrtf(wsum[0] + wsum[1]);
        const float samp = amp / norm;
        const float phase = atan2f(iw, rw);
        const float sphi = sinf(phase);
        const float cphi = cosf(phase);
        const float snc = (phase != 0.0f) ? (sphi / phase) : 1.0f;  // sinc(phase/pi)
        Wl[tid] = (samp * sphi * ph[0]) * (samp * cphi * ph[1]) * (samp * snc * ph[2]);
    }
    __syncthreads();

    // ---- conv: thread owns float4s f = tid + 256*v ----
    float* orow = out + ((size_t)b * 256 + k) * 4096;
    #pragma unroll
    for (int v = 0; v < 4; ++v) {
        const int p = 4 * (tid + 256 * v);
        float4 val = make_float4(0.0f, 0.0f, 0.0f, 0.0f);
        if (p >= ZCUT) {
            float acc[4] = {0.0f, 0.0f, 0.0f, 0.0f};
            const int base = p - 1920;  // xs[base+q] = x[p+q-2047]; base % 4 == 0
            for (int q = 0; q < QMAX; q += 4) {
                float4 w4 = *(const float4*)&Wl[q];
                float4 x0 = *(const float4*)&xs[base + q];
                float4 x1 = *(const float4*)&xs[base + q + 4];
                float win[8] = {x0.x, x0.y, x0.z, x0.w,
                                x1.x, x1.y, x1.z, x1.w};
                float wv[4] = {w4.x, w4.y, w4.z, w4.w};
                #pragma unroll
                for (int j = 0; j < 4; ++j) {
                    #pragma unroll
                    for (int r = 0; r < 4; ++r) {
                        acc[r] = fmaf(win[r + j], wv[j], acc[r]);
                    }
                }
            }
            val = make_float4(acc[0], acc[1], acc[2], acc[3]);
        }
        *(float4*)&orow[p] = val;
    }
}

// ---------------- Kernel 2: fill-shaped replicate ----------------
// Linear block id = destination row (3840 = 16 b x 240 j): consecutive blocks
// write ADJACENT 16KB regions (DRAM-sequential, mimics the 6.6 TB/s fill).
// dst out[b][j] = src out[b][j%16], j = 16..255.
__global__ __launch_bounds__(256) void replicate_rows(float* __restrict__ out) {
    const int blk = blockIdx.x;
    const int b = blk / 240;
    const int j = 16 + (blk - b * 240);
    const int k = j & 15;
    const float* __restrict__ src = out + ((size_t)b * 256 + k) * 4096;
    float* __restrict__ dst = out + ((size_t)b * 256 + j) * 4096;
    const int tid = threadIdx.x;
    #pragma unroll
    for (int v = 0; v < 4; ++v) {
        const int e = 4 * (tid + 256 * v);
        vfloat4 val = *(const vfloat4*)&src[e];
        __builtin_nontemporal_store(val, (vfloat4*)&dst[e]);
    }
}

extern "C" void kernel_launch(void* const* d_in, const int* in_sizes, int n_in,
                              void* d_out, int out_size, void* d_ws, size_t ws_size,
                              hipStream_t stream) {
    const float* x          = (const float*)d_in[0];
    const float* scales     = (const float*)d_in[1];
    const float* f_mod      = (const float*)d_in[2];
    const float* poly_mod   = (const float*)d_in[3];
    const float* exp_mod    = (const float*)d_in[4];
    const float* frac_order = (const float*)d_in[5];
    const float* phase_mod  = (const float*)d_in[6];
    const int*   istep      = (const int*)d_in[7];
    float* out = (float*)d_out;

    conv_diag<<<dim3(256), dim3(256), 0, stream>>>(
        x, scales, f_mod, poly_mod, exp_mod, frac_order, phase_mod, istep, out);

    replicate_rows<<<dim3(3840), dim3(256), 0, stream>>>(out);
}

// Round 6
// 35.540 us; speedup vs baseline: 1.1360x; 1.0063x over previous
//
#include <hip/hip_runtime.h>
#include <math.h>

#define QMAX 128   // wavelet support: gauss fp32-underflows to exact 0 beyond t~82
#define ZCUT 1920  // outputs p < ZCUT are exactly zero (x index p-1920 < 0)
#define XPAD 127   // zeros ahead of x in LDS; xs[p+q-1920] = x[p+q-2047], 16B-aligned reads
#define XLEN 2176  // x samples reachable: max index 4095+127-2047 = 2175
#define XS_SZ 2304 // XPAD + XLEN + slack (max read index 2303)

typedef float vfloat4 __attribute__((ext_vector_type(4)));  // native vec for nontemporal

// ---------------- Kernel 1: W[k] build + FIR conv of diagonal rows -> d_ws ----------
// Block bk = b*16+k: y[b,k,p] = sum_q x[b,k,p+q-2047]*W[k,q]; p<ZCUT -> 0.
// Full 16KB row (zeros included) stored to ws[bk][4096] so K2 can blind-copy.
__global__ __launch_bounds__(512) void conv_diag(const float* __restrict__ x,
                                                 const float* __restrict__ scales,
                                                 const float* __restrict__ f_mod,
                                                 const float* __restrict__ poly_mod,
                                                 const float* __restrict__ exp_mod,
                                                 const float* __restrict__ frac_order,
                                                 const float* __restrict__ phase_mod,
                                                 const int* __restrict__ istep,
                                                 float* __restrict__ ws) {
    __shared__ __attribute__((aligned(16))) float xs[XS_SZ];
    __shared__ __attribute__((aligned(16))) float Wl[QMAX];
    __shared__ float wsum[2];

    const int bk = blockIdx.x;  // 0..255 = b*16 + k
    const int k = bk & 15;
    const int tid = threadIdx.x;

    // ---- stage x[0..XLEN) behind XPAD zeros ----
    const float* xrow = x + (size_t)bk * 4096;
    for (int li = tid; li < XS_SZ; li += 512) {
        xs[li] = (li >= XPAD && li < XPAD + XLEN) ? xrow[li - XPAD] : 0.0f;
    }

    // ---- threads 0..127 compute wavelet tap amp[t] ----
    float amp = 0.0f, rw = 0.0f, iw = 0.0f;
    if (tid < QMAX) {
        const int i = istep[0];
        const float PI2 = 6.28318530717958647692f;
        const float f = 1.0f / scales[k];
        const float fm = f_mod[i];
        const float* pm = poly_mod + i * 14;
        const float em0 = exp_mod[i];
        const float* fo = frac_order + i * 12;

        const float sigma = fmaxf(fm / (PI2 * f), 1e-6f);
        const float tf = (float)tid;
        const float arg = PI2 * f * tf;
        const float br = cosf(arg);
        const float bi = sinf(arg);

        float rp = pm[0];
        float sign = -1.0f;
        for (int j = 0; j < 6; ++j) {
            float c = (float)(j + 2);
            float sp = (tf > 0.0f) ? powf(tf, fo[j]) : 0.0f;
            rp += sign * (sp * c / powf(sigma, fo[j]) * c * pm[j + 1]);
            sign = -sign;
        }
        float ipoly = pm[7];
        sign = -1.0f;
        for (int j = 6; j < 12; ++j) {
            float sp = (tf > 0.0f) ? powf(tf, fo[j]) : 0.0f;
            float term;
            if (j == 9) {
                term = sp * 5.0f / (powf(sigma, fo[j]) * 5.0f) * pm[j + 2];
            } else {
                float c = (float)(j - 4);
                term = sp * c / powf(sigma, fo[j]) * c * pm[j + 2];
            }
            ipoly += sign * term;
            sign = -sign;
        }

        const float gauss = em0 * expf(-tf * tf / (2.0f * sigma * sigma));
        rw = br * rp * gauss;
        iw = bi * ipoly * gauss;
        amp = rw + iw;

        float sq = amp * amp;
        #pragma unroll
        for (int off = 32; off > 0; off >>= 1) sq += __shfl_xor(sq, off, 64);
        if ((tid & 63) == 0) wsum[tid >> 6] = sq;
    }
    __syncthreads();

    if (tid < QMAX) {
        const int i = istep[0];
        const float* ph = phase_mod + i * 3;
        const float norm = sqrtf(wsum[0] + wsum[1]);
        const float samp = amp / norm;
        const float phase = atan2f(iw, rw);
        const float sphi = sinf(phase);
        const float cphi = cosf(phase);
        const float snc = (phase != 0.0f) ? (sphi / phase) : 1.0f;  // sinc(phase/pi)
        Wl[tid] = (samp * sphi * ph[0]) * (samp * cphi * ph[1]) * (samp * snc * ph[2]);
    }
    __syncthreads();

    // ---- conv: thread handles float4 f1 = tid (mostly zero region) and f2 = tid+512 ----
    float* wrow = ws + (size_t)bk * 4096;
    #pragma unroll
    for (int v = 0; v < 2; ++v) {
        const int fidx = tid + 512 * v;
        const int p = 4 * fidx;
        float4 val = make_float4(0.0f, 0.0f, 0.0f, 0.0f);
        if (p >= ZCUT) {
            float acc[4] = {0.0f, 0.0f, 0.0f, 0.0f};
            const int base = p - 1920;  // xs[base+q] = x[p+q-2047]; base % 4 == 0
            float4 xcur = *(const float4*)&xs[base];
            for (int q = 0; q < QMAX; q += 4) {
                float4 w4 = *(const float4*)&Wl[q];
                float4 xnxt = *(const float4*)&xs[base + q + 4];  // reused next iter
                float win[8] = {xcur.x, xcur.y, xcur.z, xcur.w,
                                xnxt.x, xnxt.y, xnxt.z, xnxt.w};
                float wv[4] = {w4.x, w4.y, w4.z, w4.w};
                #pragma unroll
                for (int j = 0; j < 4; ++j) {
                    #pragma unroll
                    for (int r = 0; r < 4; ++r) {
                        acc[r] = fmaf(win[r + j], wv[j], acc[r]);
                    }
                }
                xcur = xnxt;
            }
            val = make_float4(acc[0], acc[1], acc[2], acc[3]);
        }
        *(float4*)&wrow[p] = val;
    }
}

// ---------------- Kernel 2: fill-shaped replicate ws -> out ----------------
// Block m = b*256 + j writes out[b][j][:] = ws[b*16 + j%16][:]. Linear block
// order == linear destination order (adjacent 16KB regions, mimics the fill).
// Zero prefix (p < ZCUT) written without reading.
__global__ __launch_bounds__(256) void replicate_rows(const float* __restrict__ ws,
                                                      float* __restrict__ out) {
    const int m = blockIdx.x;            // 0..4095
    const int b = m >> 8;
    const int j = m & 255;
    const int k = j & 15;
    const float* __restrict__ src = ws + ((size_t)b * 16 + k) * 4096;
    float* __restrict__ dst = out + (size_t)m * 4096;
    const int tid = threadIdx.x;
    #pragma unroll
    for (int v = 0; v < 4; ++v) {
        const int e = 4 * (tid + 256 * v);
        vfloat4 val = (e >= ZCUT) ? *(const vfloat4*)&src[e]
                                  : (vfloat4){0.0f, 0.0f, 0.0f, 0.0f};
        __builtin_nontemporal_store(val, (vfloat4*)&dst[e]);
    }
}

extern "C" void kernel_launch(void* const* d_in, const int* in_sizes, int n_in,
                              void* d_out, int out_size, void* d_ws, size_t ws_size,
                              hipStream_t stream) {
    const float* x          = (const float*)d_in[0];
    const float* scales     = (const float*)d_in[1];
    const float* f_mod      = (const float*)d_in[2];
    const float* poly_mod   = (const float*)d_in[3];
    const float* exp_mod    = (const float*)d_in[4];
    const float* frac_order = (const float*)d_in[5];
    const float* phase_mod  = (const float*)d_in[6];
    const int*   istep      = (const int*)d_in[7];
    float* out = (float*)d_out;
    float* wsd = (float*)d_ws;  // 256 rows x 4096 floats = 4 MB scratch

    conv_diag<<<dim3(256), dim3(512), 0, stream>>>(
        x, scales, f_mod, poly_mod, exp_mod, frac_order, phase_mod, istep, wsd);

    replicate_rows<<<dim3(4096), dim3(256), 0, stream>>>(wsd, out);
}